// Round 1
// baseline (711.674 us; speedup 1.0000x reference)
//
#include <hip/hip_runtime.h>

typedef __bf16 bf16x8 __attribute__((ext_vector_type(8)));
typedef float floatx4 __attribute__((ext_vector_type(4)));

__device__ __forceinline__ unsigned short f2bf_bits(float f) {
  __bf16 h = (__bf16)f;
  return __builtin_bit_cast(unsigned short, h);
}

// ---------------------------------------------------------------------------
// prep: Pt[h][c][j] = pre_h[j] * K1_h[j][c]   (bf16 bits)
//       Qt[h][c][r] = post_h[r] * K2_h[r][c]  (f32)
// h: 0 -> (pre1,post1,K1=cos_kernel2,K2=cos_kernel1)
//    1 -> (pre2,post2,K1=sin_kernel2,K2=sin_kernel1)
//    2 -> (pre3,post3,K1=sin_kernel3,K2=cos_kernel3)
//    3 -> (pre4,post4,K1=cos_kernel4,K2=sin_kernel4)
// ---------------------------------------------------------------------------
__global__ __launch_bounds__(256) void k_prep(
    const float* __restrict__ pre1, const float* __restrict__ pre2,
    const float* __restrict__ pre3, const float* __restrict__ pre4,
    const float* __restrict__ post1, const float* __restrict__ post2,
    const float* __restrict__ post3, const float* __restrict__ post4,
    const float* __restrict__ ck1, const float* __restrict__ sk1,
    const float* __restrict__ ck2, const float* __restrict__ sk2,
    const float* __restrict__ ck3, const float* __restrict__ sk3,
    const float* __restrict__ ck4, const float* __restrict__ sk4,
    unsigned short* __restrict__ Pt, float* __restrict__ Qt)
{
  int idx = blockIdx.x * 256 + threadIdx.x;        // exactly 4*9216 threads
  int h = idx / 9216;
  int rem = idx - h * 9216;
  int c = rem / 96;
  int x = rem - c * 96;                            // j for Pt, r for Qt
  const float* pre  = (h == 0) ? pre1 : (h == 1) ? pre2 : (h == 2) ? pre3 : pre4;
  const float* post = (h == 0) ? post1 : (h == 1) ? post2 : (h == 2) ? post3 : post4;
  const float* K1   = (h == 0) ? ck2 : (h == 1) ? sk2 : (h == 2) ? sk3 : ck4;
  const float* K2   = (h == 0) ? ck1 : (h == 1) ? sk1 : (h == 2) ? ck3 : sk4;
  Pt[idx] = f2bf_bits(pre[x] * K1[x * 96 + c]);
  Qt[idx] = post[x] * K2[x * 96 + c];
}

// ---------------------------------------------------------------------------
// stage 1: one workgroup per (b,i).
//   polar[b, i*96+c] = sum_h sum_r Qt[h][c][r] * (M_{b,i,ph} @ P_h)[r,c]
// M gathered with rotation into LDS (bf16). 4 waves: wave w owns c'-tiles
// 3w..3w+2 of the 192-wide [P_a|P_b] GEMM (waves 0,1 -> helper a; 2,3 -> b).
// ---------------------------------------------------------------------------
__global__ __launch_bounds__(256) void k_stage1(
    const float* __restrict__ inputs,          // [64][2][9216]
    const unsigned short* __restrict__ Pt,     // [4][96][96] bf16
    const float* __restrict__ Qt,              // [4][96][96] f32
    unsigned short* __restrict__ polar)        // [64][9216] bf16
{
  __shared__ unsigned short Mt[96][104];       // +8 pad: bank spread, 16B-aligned rows
  __shared__ float pacc[96];

  int bi = blockIdx.x;
  int b = bi / 96;
  int i = bi - b * 96;
  int tid = threadIdx.x;
  int lane = tid & 63;
  int w = tid >> 6;

  if (tid < 96) pacc[tid] = 0.f;

  const float* srcB = inputs + (size_t)b * 18432;

  int hsel = (w >> 1);                 // helper-within-phase (wave-uniform)
  int l15 = lane & 15;
  int cbase = (w & 1) * 48 + l15;      // c' local to helper
  int kg = (lane >> 4) * 8;            // k sub-offset within 32-wide K-step
  int rg = (lane >> 4) * 4;            // row sub-offset of C/D fragment

  for (int ph = 0; ph < 2; ++ph) {
    const float* src = srcB + ph * 9216;       // ph0: R, ph1: I
    __syncthreads();                           // Mt free to overwrite; pacc init visible
    for (int e = tid; e < 9216; e += 256) {
      int r = e / 96;
      int j = e - r * 96;
      int sr = r + i; if (sr >= 96) sr -= 96;
      int sc = j + i; if (sc >= 96) sc -= 96;
      Mt[r][j] = f2bf_bits(src[sr * 96 + sc]);
    }
    __syncthreads();

    int h = ph * 2 + hsel;
    const unsigned short* PtH = Pt + h * 9216;
    const float* QtH = Qt + h * 9216;

    floatx4 acc[3][6];
    floatx4 zero = {0.f, 0.f, 0.f, 0.f};
#pragma unroll
    for (int ct = 0; ct < 3; ++ct)
#pragma unroll
      for (int rt = 0; rt < 6; ++rt)
        acc[ct][rt] = zero;

#pragma unroll
    for (int ks = 0; ks < 3; ++ks) {
      bf16x8 bfr[3];
#pragma unroll
      for (int ct = 0; ct < 3; ++ct)
        bfr[ct] = *reinterpret_cast<const bf16x8*>(PtH + (cbase + ct * 16) * 96 + ks * 32 + kg);
#pragma unroll
      for (int rt = 0; rt < 6; ++rt) {
        bf16x8 af = *reinterpret_cast<const bf16x8*>(&Mt[rt * 16 + l15][ks * 32 + kg]);
#pragma unroll
        for (int ct = 0; ct < 3; ++ct)
          acc[ct][rt] = __builtin_amdgcn_mfma_f32_16x16x32_bf16(af, bfr[ct], acc[ct][rt], 0, 0, 0);
      }
    }

    // weighted reduce over r with Qt, then cross-lane-group sum
#pragma unroll
    for (int ct = 0; ct < 3; ++ct) {
      int c = cbase + ct * 16;
      float p = 0.f;
#pragma unroll
      for (int rt = 0; rt < 6; ++rt) {
        floatx4 qv = *reinterpret_cast<const floatx4*>(QtH + c * 96 + rt * 16 + rg);
        p += qv[0] * acc[ct][rt][0] + qv[1] * acc[ct][rt][1]
           + qv[2] * acc[ct][rt][2] + qv[3] * acc[ct][rt][3];
      }
      p += __shfl_xor(p, 16);
      p += __shfl_xor(p, 32);
      if (lane < 16) atomicAdd(&pacc[c], p);
    }
  }

  __syncthreads();
  if (tid < 96) {
    polar[(size_t)b * 9216 + i * 96 + tid] = f2bf_bits(pacc[tid]);
  }
}

// ---------------------------------------------------------------------------
// stage 2: part[sp][b][m] = sum_{n in split sp} polar[b][n] * cart[m][n]
// grid (144 m-tiles of 64, 8 K-splits of 1152), 4 waves/WG, wave owns 16 m.
// cart converted f32->bf16 in-register; fully coalesced 128B row chunks.
// ---------------------------------------------------------------------------
__global__ __launch_bounds__(256) void k_stage2(
    const unsigned short* __restrict__ polar,  // [64][9216] bf16
    const float* __restrict__ cart,            // [9216][9216] f32
    float* __restrict__ part)                  // [8][64][9216] f32
{
  int tid = threadIdx.x;
  int lane = tid & 63;
  int w = tid >> 6;
  int l15 = lane & 15;
  int m = blockIdx.x * 64 + w * 16 + l15;
  int kg = (lane >> 4) * 8;
  int k0 = blockIdx.y * 1152;

  floatx4 acc[4] = {};

  const float* crow = cart + (size_t)m * 9216 + k0 + kg;
  const unsigned short* prow = polar + (size_t)l15 * 9216 + k0 + kg;

  for (int ks = 0; ks < 36; ++ks) {
    floatx4 c0 = *reinterpret_cast<const floatx4*>(crow);
    floatx4 c1 = *reinterpret_cast<const floatx4*>(crow + 4);
    bf16x8 bf;
    bf[0] = (__bf16)c0[0]; bf[1] = (__bf16)c0[1]; bf[2] = (__bf16)c0[2]; bf[3] = (__bf16)c0[3];
    bf[4] = (__bf16)c1[0]; bf[5] = (__bf16)c1[1]; bf[6] = (__bf16)c1[2]; bf[7] = (__bf16)c1[3];
#pragma unroll
    for (int bt = 0; bt < 4; ++bt) {
      bf16x8 af = *reinterpret_cast<const bf16x8*>(prow + bt * 147456);
      acc[bt] = __builtin_amdgcn_mfma_f32_16x16x32_bf16(af, bf, acc[bt], 0, 0, 0);
    }
    crow += 32;
    prow += 32;
  }

  int rg = (lane >> 4) * 4;
#pragma unroll
  for (int bt = 0; bt < 4; ++bt) {
    int b0 = bt * 16 + rg;
#pragma unroll
    for (int q = 0; q < 4; ++q) {
      part[((size_t)blockIdx.y * 64 + b0 + q) * 9216 + m] = acc[bt][q];
    }
  }
}

// ---------------------------------------------------------------------------
// reduce the 8 K-split partials into d_out (f32)
// ---------------------------------------------------------------------------
__global__ __launch_bounds__(256) void k_reduce(
    const float* __restrict__ part, float* __restrict__ out)
{
  int idx = blockIdx.x * 256 + threadIdx.x;    // exactly 589824 threads
  float s = 0.f;
#pragma unroll
  for (int sp = 0; sp < 8; ++sp) s += part[(size_t)sp * 589824 + idx];
  out[idx] = s;
}

// ---------------------------------------------------------------------------
extern "C" void kernel_launch(void* const* d_in, const int* in_sizes, int n_in,
                              void* d_out, int out_size, void* d_ws, size_t ws_size,
                              hipStream_t stream) {
  const float* inputs = (const float*)d_in[0];
  const float* cart   = (const float*)d_in[1];

  char* ws = (char*)d_ws;
  unsigned short* Pt    = (unsigned short*)(ws + 0);        //  73,728 B
  float*          Qt    = (float*)(ws + 73728);             // 147,456 B
  unsigned short* polar = (unsigned short*)(ws + 221184);   // 1,179,648 B
  float*          part  = (float*)(ws + 1400832);           // 18,874,368 B  (total ~20.3 MB)

  k_prep<<<144, 256, 0, stream>>>(
      (const float*)d_in[2],  (const float*)d_in[3],  (const float*)d_in[4],  (const float*)d_in[5],
      (const float*)d_in[6],  (const float*)d_in[7],  (const float*)d_in[8],  (const float*)d_in[9],
      (const float*)d_in[10], (const float*)d_in[11], (const float*)d_in[12], (const float*)d_in[13],
      (const float*)d_in[14], (const float*)d_in[15], (const float*)d_in[16], (const float*)d_in[17],
      Pt, Qt);

  k_stage1<<<6144, 256, 0, stream>>>(inputs, Pt, Qt, polar);

  k_stage2<<<dim3(144, 8), 256, 0, stream>>>(polar, cart, part);

  k_reduce<<<2304, 256, 0, stream>>>(part, (float*)d_out);
}